// Round 8
// baseline (336.986 us; speedup 1.0000x reference)
//
#include <hip/hip_runtime.h>
#include <stdint.h>

#define NROWS 100000
#define SDIM 150
#define HDIM 150
#define NKB 20             // K-steps of 32 (K = 4 segs x 160 padded)
#define BM 256             // rows per block = 8 waves x 32
#define BN 128             // cols per block = 32 h x 4 gates (h-major)
#define NTHREADS 512
#define KB_BYTES 8192      // panel bytes per K-step (128 cols x 64B)
#define PANEL_BYTES 163840 // 20 * 8192
#define NCB 5              // col-blocks (640/128)
#define OVW 24             // overlay row stride in f16 (48B, 16B-aligned)

using half8  = __attribute__((ext_vector_type(8))) _Float16;
using fp16x2 = __attribute__((ext_vector_type(2))) __fp16;
using floatx4 = __attribute__((ext_vector_type(4))) float;

__device__ __forceinline__ float fsig(float x) {
  return __builtin_amdgcn_rcpf(1.0f + __expf(-x));
}
__device__ __forceinline__ float ftanh(float x) {
  return 2.0f * __builtin_amdgcn_rcpf(1.0f + __expf(-2.0f * x)) - 1.0f;
}
__device__ __forceinline__ void gload_lds16(const void* g, void* l) {
  __builtin_amdgcn_global_load_lds(
      (const __attribute__((address_space(1))) void*)g,
      (__attribute__((address_space(3))) void*)l, 16, 0, 0);
}

// Pack W into 5 column-panels, each the exact LDS image:
// panel cb: cols [cb*128, cb*128+128) h-major (col = h*4 + g).
// byte(cb, cl, k) = cb*PANEL + kb*8192 + cl*64 + slot*16 + (k&7)*2
//   kb = k>>5, slot = ((k>>3)&3) ^ ((cl>>1)&3)
// k = seg*160 + kl; zero-padded kl>=150 and h>=150.
__global__ void pack_w_kernel(const float* __restrict__ w_in,
                              const float* __restrict__ w_out,
                              const float* __restrict__ u_in,
                              const float* __restrict__ u_out,
                              _Float16* __restrict__ wblk) {
  int idx = blockIdx.x * 256 + threadIdx.x;
  if (idx >= NCB * NKB * 128 * 32) return;
  int j    = idx & 7;
  int slot = (idx >> 3) & 3;
  int cl   = (idx >> 5) & 127;
  int kb   = (idx >> 12) % NKB;
  int cb   = (idx >> 12) / NKB;
  int kg   = slot ^ ((cl >> 1) & 3);
  int k    = kb * 32 + kg * 8 + j;
  int seg  = k / 160;
  int kl   = k - seg * 160;
  int col  = cb * 128 + cl;
  int g    = col & 3;        // 0=input 1=output 2=forget 3=update
  int h    = col >> 2;
  float v = 0.0f;
  if (kl < SDIM && h < HDIM) {
    const float* src = (seg == 0) ? w_in : (seg == 1) ? w_out
                     : (seg == 2) ? u_in : u_out;
    v = src[(g * SDIM + kl) * HDIM + h];
  }
  wblk[idx] = (_Float16)v;
}

// Barrier-free K-loop: W panel resident in LDS (loaded once); A loaded
// per-wave directly from global (coalesced 16 rows x 128B per frag-group),
// depth-2 register prefetch, cvt_pkrtz to f16, MFMA. No block sync in loop.
__global__ __launch_bounds__(NTHREADS, 2) void lstm_fused_kernel(
    const float* __restrict__ s_in, const float* __restrict__ s_out,
    const float* __restrict__ h_in, const float* __restrict__ h_out,
    const float* __restrict__ last_c, const float* __restrict__ bias,
    const _Float16* __restrict__ wblk,
    float* __restrict__ out_hid, float* __restrict__ out_cell) {
  __shared__ __align__(16) char lds[PANEL_BYTES];  // 160 KiB exactly

  const int tid  = threadIdx.x;
  const int lane = tid & 63;
  const int l15  = lane & 15;
  const int kgrp = lane >> 4;
  const int wid  = tid >> 6;            // 0..7
  const int cb   = blockIdx.x % NCB;    // col-panel (fast index: L3 reuse of A)
  const int rb   = blockIdx.x / NCB;
  const int row0 = rb * BM;
  const int wr0  = row0 + wid * 32;     // wave's first row

  const float* segp[4] = {s_in, s_out, h_in, h_out};

  // ---- one-time panel stage: 512 thr x 20 x 16B = 160KB (linear) ----
  {
    const char* g = (const char*)wblk + (size_t)cb * PANEL_BYTES + tid * 16;
    char* d = lds + tid * 16;
#pragma unroll
    for (int i = 0; i < 20; ++i)
      gload_lds16(g + i * 8192, d + i * 8192);
  }

  // ---- A prefetch (issued after panel loads; waits track per-register) ----
  const int r0c = min(wr0 + l15,      NROWS - 1);
  const int r1c = min(wr0 + 16 + l15, NROWS - 1);
  const size_t ro0 = (size_t)r0c * SDIM;
  const size_t ro1 = (size_t)r1c * SDIM;

  float4 pf[2][4];
  auto issueA = [&](int kb, int p) {
    const int seg = kb / 5, kk = kb % 5;
    const float* b0 = segp[seg] + ro0 + kk * 32 + kgrp * 8;
    const float* b1 = segp[seg] + ro1 + kk * 32 + kgrp * 8;
    if (kk < 4) {
      pf[p][0] = *(const float4*)b0;
      pf[p][1] = *(const float4*)(b0 + 4);
      pf[p][2] = *(const float4*)b1;
      pf[p][3] = *(const float4*)(b1 + 4);
    } else {
      // k-window 128..159: kgrp0/1 fully valid, kgrp2 has 6 valid, kgrp3 none
      if (kgrp < 2) {
        pf[p][0] = *(const float4*)b0;
        pf[p][1] = *(const float4*)(b0 + 4);
        pf[p][2] = *(const float4*)b1;
        pf[p][3] = *(const float4*)(b1 + 4);
      } else if (kgrp == 2) {
        pf[p][0] = *(const float4*)b0;                 // k 144..147
        float2 t0 = *(const float2*)(b0 + 4);          // k 148,149
        pf[p][1] = make_float4(t0.x, t0.y, 0.f, 0.f);
        pf[p][2] = *(const float4*)b1;
        float2 t1 = *(const float2*)(b1 + 4);
        pf[p][3] = make_float4(t1.x, t1.y, 0.f, 0.f);
      } else {
        pf[p][0] = pf[p][1] = pf[p][2] = pf[p][3] = make_float4(0.f, 0.f, 0.f, 0.f);
      }
    }
  };
  issueA(0, 0);
  issueA(1, 1);

  // panel (oldest 20 vm-ops) drained; the 8 newer A-loads stay in flight
  asm volatile("s_waitcnt vmcnt(8)" ::: "memory");
  __builtin_amdgcn_s_barrier();
  asm volatile("" ::: "memory");

  // per-lane panel fragment offsets (computed once)
  int bfoff[8];
#pragma unroll
  for (int n = 0; n < 8; ++n) {
    int cl = n * 16 + l15;
    bfoff[n] = cl * 64 + ((kgrp ^ ((cl >> 1) & 3)) * 16);
  }

  auto cv = [&](const float4& lo, const float4& hi) -> half8 {
    union { fp16x2 h2[4]; half8 v; } u;
    u.h2[0] = __builtin_amdgcn_cvt_pkrtz(lo.x, lo.y);
    u.h2[1] = __builtin_amdgcn_cvt_pkrtz(lo.z, lo.w);
    u.h2[2] = __builtin_amdgcn_cvt_pkrtz(hi.x, hi.y);
    u.h2[3] = __builtin_amdgcn_cvt_pkrtz(hi.z, hi.w);
    return u.v;
  };

  floatx4 acc[2][8] = {};

  // ---- barrier-free K-loop (fully unrolled: all indices static) ----
#pragma unroll
  for (int kb = 0; kb < NKB; ++kb) {
    half8 af0 = cv(pf[kb & 1][0], pf[kb & 1][1]);  // compiler waits vmcnt here
    half8 af1 = cv(pf[kb & 1][2], pf[kb & 1][3]);
    if (kb + 2 < NKB) issueA(kb + 2, kb & 1);      // refill slot just consumed
    const char* pk = lds + kb * KB_BYTES;
#pragma unroll
    for (int n = 0; n < 8; ++n) {
      half8 bf = *(const half8*)(pk + bfoff[n]);
      acc[0][n] = __builtin_amdgcn_mfma_f32_16x16x32_f16(af0, bf, acc[0][n], 0, 0, 0);
      acc[1][n] = __builtin_amdgcn_mfma_f32_16x16x32_f16(af1, bf, acc[1][n], 0, 0, 0);
    }
  }

  // ---- bias fragments ----
  float bfrag[8];
#pragma unroll
  for (int n = 0; n < 8; ++n) {
    int col = cb * 128 + n * 16 + l15;
    int h = col >> 2, g = col & 3;
    bfrag[n] = (h < HDIM) ? bias[g * HDIM + h] : 0.f;
  }

  // ---- epilogue: wave-local, chunked through tiny overlay (aliases panel) ----
  __syncthreads();  // all waves done reading the panel
  _Float16* ovl = (_Float16*)(lds) + wid * (32 * OVW);  // 1536B per wave

#pragma unroll
  for (int n = 0; n < 8; ++n) {
    asm volatile("s_waitcnt lgkmcnt(0)" ::: "memory");  // prev chunk read done
#pragma unroll
    for (int mt = 0; mt < 2; ++mt) {
#pragma unroll
      for (int i = 0; i < 4; ++i) {
        // C/D layout: col = lane&15, row = (lane>>4)*4 + i
        int rl = mt * 16 + kgrp * 4 + i;
        float gv = fsig(acc[mt][n][i] + bfrag[n]);
        ovl[rl * OVW + l15] = (_Float16)gv;
      }
    }
    asm volatile("s_waitcnt lgkmcnt(0)" ::: "memory");  // writes visible (wave-local)
    __builtin_amdgcn_sched_barrier(0);
    // consume: lane -> row rl = lane>>1, pair pr = lane&1 (2 h per item)
    {
      int rl = lane >> 1;
      int pr = lane & 1;
      long n_row = (long)wr0 + rl;
      int hg = cb * 32 + n * 4 + pr * 2;
      if (n_row < NROWS && hg < HDIM) {
        union { uint4 u; _Float16 f[8]; } gg;
        gg.u = *(const uint4*)(ovl + rl * OVW + pr * 8);
        float2 lc = *(const float2*)(last_c + (size_t)n_row * HDIM + hg);
        // f[0..3] = gates(i,o,f,u)@h ; f[4..7] = @h+1
        float c0 = (float)gg.f[2] * lc.x + (float)gg.f[3] * (float)gg.f[0];
        float c1 = (float)gg.f[6] * lc.y + (float)gg.f[7] * (float)gg.f[4];
        float hd0 = (float)gg.f[1] * ftanh(c0);
        float hd1 = (float)gg.f[5] * ftanh(c1);
        *(float2*)(out_hid  + (size_t)n_row * HDIM + hg) = make_float2(hd0, hd1);
        *(float2*)(out_cell + (size_t)n_row * HDIM + hg) = make_float2(c0, c1);
      }
    }
  }
}

extern "C" void kernel_launch(void* const* d_in, const int* in_sizes, int n_in,
                              void* d_out, int out_size, void* d_ws, size_t ws_size,
                              hipStream_t stream) {
  const float* s_in   = (const float*)d_in[0];
  const float* s_out  = (const float*)d_in[1];
  const float* h_in   = (const float*)d_in[2];
  const float* h_out  = (const float*)d_in[3];
  const float* last_c = (const float*)d_in[4];
  const float* w_in   = (const float*)d_in[5];
  const float* w_out  = (const float*)d_in[6];
  const float* u_in   = (const float*)d_in[7];
  const float* u_out  = (const float*)d_in[8];
  const float* b      = (const float*)d_in[9];

  _Float16* wblk = (_Float16*)d_ws;  // 819200 B

  pack_w_kernel<<<(NCB * NKB * 128 * 32 + 255) / 256, 256, 0, stream>>>(
      w_in, w_out, u_in, u_out, wblk);

  float* out_hid  = (float*)d_out;
  float* out_cell = out_hid + (size_t)NROWS * HDIM;

  const int nrb = (NROWS + BM - 1) / BM;  // 391
  lstm_fused_kernel<<<nrb * NCB, NTHREADS, 0, stream>>>(
      s_in, s_out, h_in, h_out, last_c, b, wblk, out_hid, out_cell);
}